// Round 2
// baseline (1447.411 us; speedup 1.0000x reference)
//
#include <hip/hip_runtime.h>

#define E_TOTAL 1600000
#define NN 100000
#define D 128      // node dim
#define ED 32      // edge dim
#define H 256      // hidden dim

typedef __attribute__((ext_vector_type(8))) short s16x8;   // 8 bf16 (one MFMA A/B frag)
typedef __attribute__((ext_vector_type(4))) short s16x4;
typedef __attribute__((ext_vector_type(4))) float f32x4;

#define MFMA(a, b, c) __builtin_amdgcn_mfma_f32_16x16x32_bf16((a), (b), (c), 0, 0, 0)

__device__ __forceinline__ short f2bf(float f) {
    unsigned u = __builtin_bit_cast(unsigned, f);
    u += 0x7fffu + ((u >> 16) & 1u);   // round-to-nearest-even
    return (short)(u >> 16);
}

// ---- prep: fp32 x -> bf16 ----
__global__ void k_cvt_x(const float* __restrict__ x, short* __restrict__ xb, int n) {
    int i = (blockIdx.x * blockDim.x + threadIdx.x) * 4;
    if (i >= n) return;
    f32x4 v = *(const f32x4*)(x + i);
    s16x4 o;
    o[0] = f2bf(v[0]); o[1] = f2bf(v[1]); o[2] = f2bf(v[2]); o[3] = f2bf(v[3]);
    *(s16x4*)(xb + i) = o;
}

// ---- prep: swizzle weight [K][N] fp32 into MFMA B-fragment order, bf16 ----
__global__ void k_swz(const float* __restrict__ W, short* __restrict__ out,
                      int K, int N, int total) {
    int idx = blockIdx.x * blockDim.x + threadIdx.x;
    if (idx >= total) return;
    int j    = idx & 7;
    int lane = (idx >> 3) & 63;
    int rest = idx >> 9;                // t*NT + nt
    int NT   = N >> 4;
    int nt   = rest % NT;
    int t    = rest / NT;
    int k    = t * 32 + (lane >> 4) * 8 + j;
    int col  = nt * 16 + (lane & 15);
    float v  = (k < K) ? W[k * N + col] : 0.f;
    out[idx] = f2bf(v);
}

// ---- sort prep: histogram of dst ----
__global__ void k_hist(const int* __restrict__ ei, int* __restrict__ cnt) {
    int e = blockIdx.x * blockDim.x + threadIdx.x;
    if (e >= E_TOTAL) return;
    atomicAdd(&cnt[ei[E_TOTAL + e]], 1);
}

// ---- sort prep: in-place exclusive scan of cnt[0..n) (single block, 1024 thr) ----
__global__ void k_scan(int* __restrict__ cnt, int n) {
    __shared__ int wsum[16];
    __shared__ int woff[16];
    __shared__ int carry;
    const int tid = threadIdx.x, lane = tid & 63, wv = tid >> 6;
    if (tid == 0) carry = 0;
    __syncthreads();
    for (int base = 0; base < n; base += 1024) {
        int i = base + tid;
        int v = (i < n) ? cnt[i] : 0;
        int s = v;
#pragma unroll
        for (int off = 1; off < 64; off <<= 1) {
            int u = __shfl_up(s, off, 64);
            if (lane >= off) s += u;
        }
        if (lane == 63) wsum[wv] = s;
        __syncthreads();
        if (wv == 0 && lane < 16) {
            int t = wsum[lane];
            int sc = t;
#pragma unroll
            for (int off = 1; off < 16; off <<= 1) {
                int u = __shfl_up(sc, off, 16);
                if (lane >= off) sc += u;
            }
            woff[lane] = sc - t;            // exclusive wave offset
            if (lane == 15) wsum[0] = sc;   // chunk total (reads of wsum[lane] precede in-wave)
        }
        __syncthreads();
        if (i < n) cnt[i] = (s - v) + woff[wv] + carry;
        __syncthreads();                    // all carry reads done
        if (tid == 0) carry += wsum[0];
        __syncthreads();
    }
}

// ---- sort prep: scatter edges into dst-sorted order ----
__global__ void k_perm(const int* __restrict__ ei, int* __restrict__ cursor,
                       int* __restrict__ perm, int2* __restrict__ srcdst) {
    int e = blockIdx.x * blockDim.x + threadIdx.x;
    if (e >= E_TOTAL) return;
    int s = ei[e], d = ei[E_TOTAL + e];
    int pos = atomicAdd(&cursor[d], 1);
    perm[pos] = e;
    srcdst[pos] = make_int2(s, d);
}

// ---- edge MLP + segment-reduced scatter-add ----
// Edges processed in dst-sorted order: x[dst] gathers are runs (L1 hits) and the
// scatter is segment-reduced in LDS -> ~one coalesced atomic burst per distinct dst
// per block instead of 8192 scattered dword atomics.
__global__ __launch_bounds__(128, 2)
void k_edge(const short* __restrict__ xb, const int* __restrict__ perm,
            const int2* __restrict__ srcdst,
            const float* __restrict__ eattr, const float* __restrict__ cong,
            const short* __restrict__ W1s, const float* __restrict__ b1,
            const short* __restrict__ W2s, const float* __restrict__ b2,
            float* __restrict__ agg) {
    // union: bf16 hb[64][264] (layer1->2) aliases f32 mbuf[64][132] (epilogue).
    // Row stride is 528 B in both; wave w only touches rows [w*32, w*32+32) until
    // the final barrier, so the aliasing is wave-private.
    __shared__ char smem[64 * 528];
    __shared__ int dst_s[64];
    short (*hb)[H + 8]  = (short (*)[H + 8])smem;
    float (*mbuf)[132]  = (float (*)[132])smem;

    const int lane = threadIdx.x & 63;
    const int w    = threadIdx.x >> 6;  // wave id (0..1), owns sorted positions [w*32, w*32+32)
    const int m    = lane & 15;
    const int q    = lane >> 4;
    const int p0b  = blockIdx.x * 64;
    const int p0   = p0b + w * 32;
    const int pa   = p0 + m;
    const int pb   = p0 + 16 + m;

    if (threadIdx.x < 64) dst_s[threadIdx.x] = srcdst[p0b + threadIdx.x].y;

    const int  ea  = perm[pa];
    const int  eb  = perm[pb];
    const int2 sda = srcdst[pa];
    const int2 sdb = srcdst[pb];
    const int src0 = sda.x, dst0 = sda.y;
    const int src1 = sdb.x, dst1 = sdb.y;

    // ---- layer 1: [32 x 320] @ [320 x 256] ----
    f32x4 acc[16][2];
#pragma unroll
    for (int n = 0; n < 16; n++) {
        acc[n][0] = (f32x4){0.f, 0.f, 0.f, 0.f};
        acc[n][1] = (f32x4){0.f, 0.f, 0.f, 0.f};
    }

    const short* a0s = xb + (long)src0 * D + q * 8;
    const short* a0d = xb + (long)dst0 * D + q * 8;   // runs of equal dst -> L1 hits
    const short* a1s = xb + (long)src1 * D + q * 8;
    const short* a1d = xb + (long)dst1 * D + q * 8;

#pragma unroll
    for (int t = 0; t < 10; t++) {
        s16x8 a0, a1;
        if (t < 4) {
            a0 = *(const s16x8*)(a0s + t * 32);
            a1 = *(const s16x8*)(a1s + t * 32);
        } else if (t < 8) {
            a0 = *(const s16x8*)(a0d + (t - 4) * 32);
            a1 = *(const s16x8*)(a1d + (t - 4) * 32);
        } else if (t == 8) {
            const float* pe0 = eattr + (long)ea * ED + q * 8;
            const float* pe1 = eattr + (long)eb * ED + q * 8;
            f32x4 v00 = *(const f32x4*)pe0, v01 = *(const f32x4*)(pe0 + 4);
            f32x4 v10 = *(const f32x4*)pe1, v11 = *(const f32x4*)(pe1 + 4);
#pragma unroll
            for (int j = 0; j < 4; j++) {
                a0[j] = f2bf(v00[j]); a0[4 + j] = f2bf(v01[j]);
                a1[j] = f2bf(v10[j]); a1[4 + j] = f2bf(v11[j]);
            }
        } else {
            a0 = (s16x8){0, 0, 0, 0, 0, 0, 0, 0};
            a1 = (s16x8){0, 0, 0, 0, 0, 0, 0, 0};
            if (q == 0) {                       // k=288 is the congestion feature
                a0[0] = f2bf(cong[src0]);
                a1[0] = f2bf(cong[src1]);
            }
        }
        const short* wp = W1s + (t * 16) * 512 + lane * 8;
#pragma unroll
        for (int n = 0; n < 16; n++) {
            s16x8 b = *(const s16x8*)(wp + n * 512);
            acc[n][0] = MFMA(a0, b, acc[n][0]);
            acc[n][1] = MFMA(a1, b, acc[n][1]);
        }
    }

    // epilogue 1: +bias, relu, bf16 -> LDS (C-layout -> A-layout transform)
#pragma unroll
    for (int n = 0; n < 16; n++) {
        int col = n * 16 + m;
        float bias = b1[col];
#pragma unroll
        for (int mb = 0; mb < 2; mb++) {
#pragma unroll
            for (int r = 0; r < 4; r++) {
                int row = w * 32 + mb * 16 + q * 4 + r;
                float v = acc[n][mb][r] + bias;
                hb[row][col] = f2bf(v > 0.f ? v : 0.f);
            }
        }
    }
    // wave-private rows: no barrier needed before layer 2

    // ---- layer 2: [32 x 256] @ [256 x 128] ----
    f32x4 acc2[8][2];
#pragma unroll
    for (int n = 0; n < 8; n++) {
        acc2[n][0] = (f32x4){0.f, 0.f, 0.f, 0.f};
        acc2[n][1] = (f32x4){0.f, 0.f, 0.f, 0.f};
    }
#pragma unroll
    for (int t = 0; t < 8; t++) {
        s16x8 a0 = *(const s16x8*)&hb[w * 32 + m][t * 32 + q * 8];
        s16x8 a1 = *(const s16x8*)&hb[w * 32 + 16 + m][t * 32 + q * 8];
        const short* wp = W2s + (t * 8) * 512 + lane * 8;
#pragma unroll
        for (int n = 0; n < 8; n++) {
            s16x8 b = *(const s16x8*)(wp + n * 512);
            acc2[n][0] = MFMA(a0, b, acc2[n][0]);
            acc2[n][1] = MFMA(a1, b, acc2[n][1]);
        }
    }

    __syncthreads();   // orders hb(short) reads before mbuf(float) writes (alias) across compiler

    // epilogue 2: +bias, f32 messages -> LDS
#pragma unroll
    for (int mb = 0; mb < 2; mb++) {
#pragma unroll
        for (int r = 0; r < 4; r++) {
            int row = w * 32 + mb * 16 + q * 4 + r;
#pragma unroll
            for (int n = 0; n < 8; n++) {
                mbuf[row][n * 16 + m] = acc2[n][mb][r] + b2[n * 16 + m];
            }
        }
    }
    __syncthreads();

    // segment-reduce 64 sorted rows; one coalesced atomic burst per distinct dst
    const int c = threadIdx.x;   // 0..127: one column per thread
    float s = 0.f;
    int prev = dst_s[0];
    for (int row = 0; row < 64; row++) {
        int dcur = dst_s[row];
        if (dcur != prev) {      // uniform branch: dst sequence identical across threads
            __hip_atomic_fetch_add(agg + (long)prev * D + c, s,
                                   __ATOMIC_RELAXED, __HIP_MEMORY_SCOPE_AGENT);
            s = 0.f; prev = dcur;
        }
        s += mbuf[row][c];
    }
    __hip_atomic_fetch_add(agg + (long)prev * D + c, s,
                           __ATOMIC_RELAXED, __HIP_MEMORY_SCOPE_AGENT);
}

// ---- node MLP (M=32/wave) ----
__global__ __launch_bounds__(128, 2)
void k_node(const short* __restrict__ xb, const float* __restrict__ agg,
            const short* __restrict__ U1s, const float* __restrict__ b1,
            const short* __restrict__ U2s, const float* __restrict__ b2,
            float* __restrict__ out) {
    __shared__ short hbuf[64][H + 8];
    const int lane = threadIdx.x & 63;
    const int w    = threadIdx.x >> 6;
    const int m    = lane & 15;
    const int q    = lane >> 4;
    const int r0   = blockIdx.x * 64 + w * 32;
    int rowa = r0 + m;
    int rowb = r0 + 16 + m;
    int rca  = rowa < NN ? rowa : 0;    // clamp gathers; stores are guarded
    int rcb  = rowb < NN ? rowb : 0;

    f32x4 acc[16][2];
#pragma unroll
    for (int n = 0; n < 16; n++) {
        acc[n][0] = (f32x4){0.f, 0.f, 0.f, 0.f};
        acc[n][1] = (f32x4){0.f, 0.f, 0.f, 0.f};
    }

#pragma unroll
    for (int t = 0; t < 8; t++) {
        s16x8 a0, a1;
        if (t < 4) {
            a0 = *(const s16x8*)(xb + (long)rca * D + t * 32 + q * 8);
            a1 = *(const s16x8*)(xb + (long)rcb * D + t * 32 + q * 8);
        } else {
            const float* p0 = agg + (long)rca * D + (t - 4) * 32 + q * 8;
            const float* p1 = agg + (long)rcb * D + (t - 4) * 32 + q * 8;
            f32x4 v00 = *(const f32x4*)p0, v01 = *(const f32x4*)(p0 + 4);
            f32x4 v10 = *(const f32x4*)p1, v11 = *(const f32x4*)(p1 + 4);
#pragma unroll
            for (int j = 0; j < 4; j++) {
                a0[j] = f2bf(v00[j]); a0[4 + j] = f2bf(v01[j]);
                a1[j] = f2bf(v10[j]); a1[4 + j] = f2bf(v11[j]);
            }
        }
        const short* wp = U1s + (t * 16) * 512 + lane * 8;
#pragma unroll
        for (int n = 0; n < 16; n++) {
            s16x8 b = *(const s16x8*)(wp + n * 512);
            acc[n][0] = MFMA(a0, b, acc[n][0]);
            acc[n][1] = MFMA(a1, b, acc[n][1]);
        }
    }

#pragma unroll
    for (int n = 0; n < 16; n++) {
        int col = n * 16 + m;
        float bias = b1[col];
#pragma unroll
        for (int mb = 0; mb < 2; mb++) {
#pragma unroll
            for (int r = 0; r < 4; r++) {
                int row = w * 32 + mb * 16 + q * 4 + r;
                float v = acc[n][mb][r] + bias;
                hbuf[row][col] = f2bf(v > 0.f ? v : 0.f);
            }
        }
    }

    f32x4 acc2[8][2];
#pragma unroll
    for (int n = 0; n < 8; n++) {
        acc2[n][0] = (f32x4){0.f, 0.f, 0.f, 0.f};
        acc2[n][1] = (f32x4){0.f, 0.f, 0.f, 0.f};
    }
#pragma unroll
    for (int t = 0; t < 8; t++) {
        s16x8 a0 = *(const s16x8*)&hbuf[w * 32 + m][t * 32 + q * 8];
        s16x8 a1 = *(const s16x8*)&hbuf[w * 32 + 16 + m][t * 32 + q * 8];
        const short* wp = U2s + (t * 8) * 512 + lane * 8;
#pragma unroll
        for (int n = 0; n < 8; n++) {
            s16x8 b = *(const s16x8*)(wp + n * 512);
            acc2[n][0] = MFMA(a0, b, acc2[n][0]);
            acc2[n][1] = MFMA(a1, b, acc2[n][1]);
        }
    }

#pragma unroll
    for (int mb = 0; mb < 2; mb++) {
#pragma unroll
        for (int r = 0; r < 4; r++) {
            int orow = r0 + mb * 16 + q * 4 + r;
            if (orow < NN) {
#pragma unroll
                for (int n = 0; n < 8; n++) {
                    out[(long)orow * D + n * 16 + m] = acc2[n][mb][r] + b2[n * 16 + m];
                }
            }
        }
    }
}

extern "C" void kernel_launch(void* const* d_in, const int* in_sizes, int n_in,
                              void* d_out, int out_size, void* d_ws, size_t ws_size,
                              hipStream_t stream) {
    const float* x     = (const float*)d_in[0];
    const int*   ei    = (const int*)d_in[1];
    const float* eattr = (const float*)d_in[2];
    const float* cong  = (const float*)d_in[3];
    const float* mW1   = (const float*)d_in[4];
    const float* mb1   = (const float*)d_in[5];
    const float* mW2   = (const float*)d_in[6];
    const float* mb2   = (const float*)d_in[7];
    const float* uW1   = (const float*)d_in[8];
    const float* ub1   = (const float*)d_in[9];
    const float* uW2   = (const float*)d_in[10];
    const float* ub2   = (const float*)d_in[11];

    char* ws = (char*)d_ws;
    float* agg    = (float*)ws;                     // 51,200,000 B
    short* xb     = (short*)(ws + 51200000);        // 25,600,000 B
    short* W1s    = (short*)(ws + 76800000);        //    163,840 B (K padded 289->320)
    short* W2s    = (short*)(ws + 76963840);        //     65,536 B
    short* U1s    = (short*)(ws + 77029376);        //    131,072 B
    short* U2s    = (short*)(ws + 77160448);        //     65,536 B
    int*   cnt    = (int*)(ws + 77225984);          //    400,000 B (becomes cursor after scan)
    int*   perm   = (int*)(ws + 77625984);          //  6,400,000 B
    int2*  srcdst = (int2*)(ws + 84025984);         // 12,800,000 B  (total ~96.8 MB)

    hipMemsetAsync(agg, 0, (size_t)NN * D * sizeof(float), stream);
    hipMemsetAsync(cnt, 0, (size_t)NN * sizeof(int), stream);

    k_cvt_x<<<(NN * D / 4 + 255) / 256, 256, 0, stream>>>(x, xb, NN * D);

    int tW1 = 10 * 16 * 512, tW2 = 8 * 8 * 512, tU1 = 8 * 16 * 512, tU2 = 8 * 8 * 512;
    k_swz<<<(tW1 + 255) / 256, 256, 0, stream>>>(mW1, W1s, 289, 256, tW1);
    k_swz<<<(tW2 + 255) / 256, 256, 0, stream>>>(mW2, W2s, 256, 128, tW2);
    k_swz<<<(tU1 + 255) / 256, 256, 0, stream>>>(uW1, U1s, 256, 256, tU1);
    k_swz<<<(tU2 + 255) / 256, 256, 0, stream>>>(uW2, U2s, 256, 128, tU2);

    // counting sort by dst
    k_hist<<<(E_TOTAL + 255) / 256, 256, 0, stream>>>(ei, cnt);
    k_scan<<<1, 1024, 0, stream>>>(cnt, NN);
    k_perm<<<(E_TOTAL + 255) / 256, 256, 0, stream>>>(ei, cnt, perm, srcdst);

    // 64 sorted edges per 128-thread block (2 waves x 32)
    k_edge<<<E_TOTAL / 64, 128, 0, stream>>>(xb, perm, srcdst, eattr, cong,
                                             W1s, mb1, W2s, mb2, agg);
    k_node<<<(NN + 63) / 64, 128, 0, stream>>>(xb, agg, U1s, ub1, U2s, ub2, (float*)d_out);
}

// Round 3
// 1175.771 us; speedup vs baseline: 1.2310x; 1.2310x over previous
//
#include <hip/hip_runtime.h>

#define E_TOTAL 1600000
#define NN 100000
#define D 128      // node dim
#define ED 32      // edge dim
#define H 256      // hidden dim

typedef __attribute__((ext_vector_type(8))) short s16x8;   // 8 bf16 (one MFMA A/B frag)
typedef __attribute__((ext_vector_type(4))) short s16x4;
typedef __attribute__((ext_vector_type(4))) float f32x4;

#define MFMA(a, b, c) __builtin_amdgcn_mfma_f32_16x16x32_bf16((a), (b), (c), 0, 0, 0)

__device__ __forceinline__ short f2bf(float f) {
    unsigned u = __builtin_bit_cast(unsigned, f);
    u += 0x7fffu + ((u >> 16) & 1u);   // round-to-nearest-even
    return (short)(u >> 16);
}

// async global->LDS, 16B per lane; LDS dest is wave-uniform base (HW adds lane*16)
__device__ __forceinline__ void gll16(const void* g, void* l) {
    __builtin_amdgcn_global_load_lds(
        (const __attribute__((address_space(1))) void*)g,
        (__attribute__((address_space(3))) void*)l, 16, 0, 0);
}

// ---- prep: fp32 x -> bf16 ----
__global__ void k_cvt_x(const float* __restrict__ x, short* __restrict__ xb, int n) {
    int i = (blockIdx.x * blockDim.x + threadIdx.x) * 4;
    if (i >= n) return;
    f32x4 v = *(const f32x4*)(x + i);
    s16x4 o;
    o[0] = f2bf(v[0]); o[1] = f2bf(v[1]); o[2] = f2bf(v[2]); o[3] = f2bf(v[3]);
    *(s16x4*)(xb + i) = o;
}

// ---- prep: swizzle weight [K][N] fp32 into MFMA B-fragment order, bf16 ----
__global__ void k_swz(const float* __restrict__ W, short* __restrict__ out,
                      int K, int N, int total) {
    int idx = blockIdx.x * blockDim.x + threadIdx.x;
    if (idx >= total) return;
    int j    = idx & 7;
    int lane = (idx >> 3) & 63;
    int rest = idx >> 9;                // t*NT + nt
    int NT   = N >> 4;
    int nt   = rest % NT;
    int t    = rest / NT;
    int k    = t * 32 + (lane >> 4) * 8 + j;
    int col  = nt * 16 + (lane & 15);
    float v  = (k < K) ? W[k * N + col] : 0.f;
    out[idx] = f2bf(v);
}

// ---- sort prep: histogram of dst ----
__global__ void k_hist(const int* __restrict__ ei, int* __restrict__ cnt) {
    int e = blockIdx.x * blockDim.x + threadIdx.x;
    if (e >= E_TOTAL) return;
    atomicAdd(&cnt[ei[E_TOTAL + e]], 1);
}

// ---- hierarchical scan: per-block exclusive scan + block totals ----
__global__ void k_scan1(int* __restrict__ cnt, int* __restrict__ psum, int n) {
    __shared__ int wsum[16];
    __shared__ int woff[16];
    const int tid = threadIdx.x, lane = tid & 63, wv = tid >> 6;
    int i = blockIdx.x * 1024 + tid;
    int v = (i < n) ? cnt[i] : 0;
    int s = v;
#pragma unroll
    for (int off = 1; off < 64; off <<= 1) {
        int u = __shfl_up(s, off, 64);
        if (lane >= off) s += u;
    }
    if (lane == 63) wsum[wv] = s;
    __syncthreads();
    if (wv == 0 && lane < 16) {
        int t = wsum[lane];
        int sc = t;
#pragma unroll
        for (int off = 1; off < 16; off <<= 1) {
            int u = __shfl_up(sc, off, 16);
            if (lane >= off) sc += u;
        }
        woff[lane] = sc - t;
    }
    __syncthreads();
    int excl = (s - v) + woff[wv];
    if (i < n) cnt[i] = excl;
    if (tid == 1023) psum[blockIdx.x] = excl + v;   // block total
}

// ---- scan the 98 block totals (one small block) ----
__global__ void k_scan2(int* __restrict__ psum, int nb) {
    __shared__ int w0;
    const int tid = threadIdx.x, lane = tid & 63, wv = tid >> 6;
    int v = (tid < nb) ? psum[tid] : 0;
    int s = v;
#pragma unroll
    for (int off = 1; off < 64; off <<= 1) {
        int u = __shfl_up(s, off, 64);
        if (lane >= off) s += u;
    }
    if (wv == 0 && lane == 63) w0 = s;
    __syncthreads();
    int excl = (s - v) + (wv ? w0 : 0);
    if (tid < nb) psum[tid] = excl;
}

// ---- add block offsets back ----
__global__ void k_scan3(const int* __restrict__ psum, int* __restrict__ cnt, int n) {
    int i = blockIdx.x * 1024 + threadIdx.x;
    if (i < n) cnt[i] += psum[blockIdx.x];
}

// ---- sort prep: scatter edges into dst-sorted order ----
__global__ void k_perm(const int* __restrict__ ei, int* __restrict__ cursor,
                       int* __restrict__ perm, int2* __restrict__ srcdst) {
    int e = blockIdx.x * blockDim.x + threadIdx.x;
    if (e >= E_TOTAL) return;
    int s = ei[e], d = ei[E_TOTAL + e];
    int pos = atomicAdd(&cursor[d], 1);
    perm[pos] = e;
    srcdst[pos] = make_int2(s, d);
}

// A-fragment gather (layer 1), T is compile-time after unroll
#define LOAD_AFRAG(T, A0, A1)                                                \
    if ((T) < 4) {                                                           \
        A0 = *(const s16x8*)(a0s + (T) * 32);                                \
        A1 = *(const s16x8*)(a1s + (T) * 32);                                \
    } else if ((T) < 8) {                                                    \
        A0 = *(const s16x8*)(a0d + ((T) - 4) * 32);                          \
        A1 = *(const s16x8*)(a1d + ((T) - 4) * 32);                          \
    } else if ((T) == 8) {                                                   \
        const float* pe0 = eattr + (long)ea * ED + q * 8;                    \
        const float* pe1 = eattr + (long)eb * ED + q * 8;                    \
        f32x4 v00 = *(const f32x4*)pe0, v01 = *(const f32x4*)(pe0 + 4);      \
        f32x4 v10 = *(const f32x4*)pe1, v11 = *(const f32x4*)(pe1 + 4);      \
        for (int j = 0; j < 4; j++) {                                        \
            A0[j] = f2bf(v00[j]); A0[4 + j] = f2bf(v01[j]);                  \
            A1[j] = f2bf(v10[j]); A1[4 + j] = f2bf(v11[j]);                  \
        }                                                                    \
    } else {                                                                 \
        A0 = (s16x8){0, 0, 0, 0, 0, 0, 0, 0};                               \
        A1 = (s16x8){0, 0, 0, 0, 0, 0, 0, 0};                               \
        if (q == 0) { A0[0] = f2bf(cong[sda.x]); A1[0] = f2bf(cong[sdb.x]); } \
    }

// ---- edge MLP + segment-reduced scatter-add, LDS-staged weights ----
// 4 waves x 32 edges = 128 edges/block. Weight chunks double-buffered in LDS
// (2x16KB), staged via global_load_lds (each wave stages a quarter), consumed
// by all 4 waves as ds_read_b128. 2-phase template: stage(c+1) || compute(c),
// one full-drain barrier per chunk. hbuf = 16 rows/wave; layer 2 runs twice
// (mb=0 then mb=1) with W2 re-staged. LDS: wbuf 32K + hbuf 33K, epilogue mbuf
// (67.6K) aliases both -> 68.1KB/block -> 2 blocks/CU.
__global__ __launch_bounds__(256, 2)
void k_edge(const short* __restrict__ xb, const int* __restrict__ perm,
            const int2* __restrict__ srcdst,
            const float* __restrict__ eattr, const float* __restrict__ cong,
            const short* __restrict__ W1s, const float* __restrict__ b1,
            const short* __restrict__ W2s, const float* __restrict__ b2,
            float* __restrict__ agg) {
    __shared__ char smem[67584];        // wbuf[2][16K] @0, hbuf @32768; mbuf aliases all
    __shared__ int dst_s[128];
    short (*hb)[264]   = (short (*)[264])(smem + 32768);  // [64 rows][256+8 pad]
    float (*mbuf)[132] = (float (*)[132])smem;            // [128 rows][128+4 pad]

    const int tid  = threadIdx.x;
    const int lane = tid & 63;
    const int w    = tid >> 6;          // wave 0..3, owns sorted positions [w*32, w*32+32)
    const int m    = lane & 15;
    const int q    = lane >> 4;
    const int p0b  = blockIdx.x * 128;
    const int pa   = p0b + w * 32 + m;
    const int pb   = pa + 16;

    if (tid < 128) dst_s[tid] = srcdst[p0b + tid].y;

    const int  ea  = perm[pa];
    const int  eb  = perm[pb];
    const int2 sda = srcdst[pa];
    const int2 sdb = srcdst[pb];

    // stage W1 chunk 0 into buf0 (each wave stages 4KB = 4 x 1KB)
    {
        const char* g = (const char*)W1s + w * 4096 + lane * 16;
        char* l = smem + w * 4096;
        gll16(g, l); gll16(g + 1024, l + 1024);
        gll16(g + 2048, l + 2048); gll16(g + 3072, l + 3072);
    }
    __syncthreads();

    // ---- layer 1: [32 x 320] @ [320 x 256] ----
    f32x4 acc[16][2];
#pragma unroll
    for (int n = 0; n < 16; n++) {
        acc[n][0] = (f32x4){0.f, 0.f, 0.f, 0.f};
        acc[n][1] = (f32x4){0.f, 0.f, 0.f, 0.f};
    }

    const short* a0s = xb + (long)sda.x * D + q * 8;
    const short* a0d = xb + (long)sda.y * D + q * 8;   // sorted: runs of equal dst -> L1 hits
    const short* a1s = xb + (long)sdb.x * D + q * 8;
    const short* a1d = xb + (long)sdb.y * D + q * 8;

    s16x8 a0, a1, a0n, a1n;
    LOAD_AFRAG(0, a0, a1);

#pragma unroll
    for (int t = 0; t < 10; t++) {
        if (t < 9) { LOAD_AFRAG(t + 1, a0n, a1n); }    // reg prefetch of next A-frags
        // async prefetch of next weight chunk into the other buffer
        if (t < 9) {
            const char* g = (const char*)W1s + (t + 1) * 16384 + w * 4096 + lane * 16;
            char* l = smem + ((t + 1) & 1) * 16384 + w * 4096;
            gll16(g, l); gll16(g + 1024, l + 1024);
            gll16(g + 2048, l + 2048); gll16(g + 3072, l + 3072);
        } else {                                       // W2 chunk 0 -> buf0
            const char* g = (const char*)W2s + w * 2048 + lane * 16;
            char* l = smem + w * 2048;
            gll16(g, l); gll16(g + 1024, l + 1024);
        }
        const char* wp = smem + (t & 1) * 16384 + lane * 16;
#pragma unroll
        for (int n = 0; n < 16; n++) {
            s16x8 b = *(const s16x8*)(wp + n * 1024);
            acc[n][0] = MFMA(a0, b, acc[n][0]);
            acc[n][1] = MFMA(a1, b, acc[n][1]);
        }
        __syncthreads();                               // chunk t consumed; chunk t+1 staged
        if (t < 9) { a0 = a0n; a1 = a1n; }
    }

    // ---- layer 2: [32 x 256] @ [256 x 128], two passes (mb=0,1) over 16-row hbuf ----
    f32x4 acc2[8][2];
#pragma unroll
    for (int n = 0; n < 8; n++) {
        acc2[n][0] = (f32x4){0.f, 0.f, 0.f, 0.f};
        acc2[n][1] = (f32x4){0.f, 0.f, 0.f, 0.f};
    }

#pragma unroll
    for (int pass = 0; pass < 2; pass++) {
        // epilogue 1 for this pass: +bias, relu, bf16 -> wave-private hbuf rows
#pragma unroll
        for (int n = 0; n < 16; n++) {
            float bias = b1[n * 16 + m];
#pragma unroll
            for (int r = 0; r < 4; r++) {
                float v = acc[n][pass][r] + bias;
                hb[w * 16 + q * 4 + r][n * 16 + m] = f2bf(v > 0.f ? v : 0.f);
            }
        }
#pragma unroll
        for (int t = 0; t < 8; t++) {
            if (t < 7) {                               // prefetch next W2 chunk
                const char* g = (const char*)W2s + (t + 1) * 8192 + w * 2048 + lane * 16;
                char* l = smem + ((t + 1) & 1) * 16384 + w * 2048;
                gll16(g, l); gll16(g + 1024, l + 1024);
            } else if (pass == 0) {                    // re-stage W2 chunk 0 for pass 1
                const char* g = (const char*)W2s + w * 2048 + lane * 16;
                char* l = smem + w * 2048;
                gll16(g, l); gll16(g + 1024, l + 1024);
            }
            s16x8 a = *(const s16x8*)&hb[w * 16 + m][t * 32 + q * 8];
            const char* wp = smem + (t & 1) * 16384 + lane * 16;
#pragma unroll
            for (int n = 0; n < 8; n++) {
                s16x8 b = *(const s16x8*)(wp + n * 1024);
                acc2[n][pass] = MFMA(a, b, acc2[n][pass]);
            }
            __syncthreads();
        }
    }

    // epilogue 2: +bias, f32 messages -> mbuf (aliases wbuf+hbuf; all reads drained
    // by the final loop barrier above)
#pragma unroll
    for (int mb = 0; mb < 2; mb++) {
#pragma unroll
        for (int r = 0; r < 4; r++) {
            int row = w * 32 + mb * 16 + q * 4 + r;
#pragma unroll
            for (int n = 0; n < 8; n++) {
                mbuf[row][n * 16 + m] = acc2[n][mb][r] + b2[n * 16 + m];
            }
        }
    }
    __syncthreads();

    // segment-reduce 128 sorted rows (two 64-row halves; atomics fix the seam)
    const int half = tid >> 7;          // 0 or 1
    const int cc   = tid & 127;
    float s = 0.f;
    int prev = dst_s[half * 64];
    for (int row = half * 64; row < half * 64 + 64; row++) {
        int dcur = dst_s[row];
        if (dcur != prev) {             // uniform per half
            __hip_atomic_fetch_add(agg + (long)prev * D + cc, s,
                                   __ATOMIC_RELAXED, __HIP_MEMORY_SCOPE_AGENT);
            s = 0.f; prev = dcur;
        }
        s += mbuf[row][cc];
    }
    __hip_atomic_fetch_add(agg + (long)prev * D + cc, s,
                           __ATOMIC_RELAXED, __HIP_MEMORY_SCOPE_AGENT);
}

// ---- node MLP (M=32/wave) ----
__global__ __launch_bounds__(128, 2)
void k_node(const short* __restrict__ xb, const float* __restrict__ agg,
            const short* __restrict__ U1s, const float* __restrict__ b1,
            const short* __restrict__ U2s, const float* __restrict__ b2,
            float* __restrict__ out) {
    __shared__ short hbuf[64][H + 8];
    const int lane = threadIdx.x & 63;
    const int w    = threadIdx.x >> 6;
    const int m    = lane & 15;
    const int q    = lane >> 4;
    const int r0   = blockIdx.x * 64 + w * 32;
    int rowa = r0 + m;
    int rowb = r0 + 16 + m;
    int rca  = rowa < NN ? rowa : 0;    // clamp gathers; stores are guarded
    int rcb  = rowb < NN ? rowb : 0;

    f32x4 acc[16][2];
#pragma unroll
    for (int n = 0; n < 16; n++) {
        acc[n][0] = (f32x4){0.f, 0.f, 0.f, 0.f};
        acc[n][1] = (f32x4){0.f, 0.f, 0.f, 0.f};
    }

#pragma unroll
    for (int t = 0; t < 8; t++) {
        s16x8 a0, a1;
        if (t < 4) {
            a0 = *(const s16x8*)(xb + (long)rca * D + t * 32 + q * 8);
            a1 = *(const s16x8*)(xb + (long)rcb * D + t * 32 + q * 8);
        } else {
            const float* p0 = agg + (long)rca * D + (t - 4) * 32 + q * 8;
            const float* p1 = agg + (long)rcb * D + (t - 4) * 32 + q * 8;
            f32x4 v00 = *(const f32x4*)p0, v01 = *(const f32x4*)(p0 + 4);
            f32x4 v10 = *(const f32x4*)p1, v11 = *(const f32x4*)(p1 + 4);
#pragma unroll
            for (int j = 0; j < 4; j++) {
                a0[j] = f2bf(v00[j]); a0[4 + j] = f2bf(v01[j]);
                a1[j] = f2bf(v10[j]); a1[4 + j] = f2bf(v11[j]);
            }
        }
        const short* wp = U1s + (t * 16) * 512 + lane * 8;
#pragma unroll
        for (int n = 0; n < 16; n++) {
            s16x8 b = *(const s16x8*)(wp + n * 512);
            acc[n][0] = MFMA(a0, b, acc[n][0]);
            acc[n][1] = MFMA(a1, b, acc[n][1]);
        }
    }

#pragma unroll
    for (int n = 0; n < 16; n++) {
        int col = n * 16 + m;
        float bias = b1[col];
#pragma unroll
        for (int mb = 0; mb < 2; mb++) {
#pragma unroll
            for (int r = 0; r < 4; r++) {
                int row = w * 32 + mb * 16 + q * 4 + r;
                float v = acc[n][mb][r] + bias;
                hbuf[row][col] = f2bf(v > 0.f ? v : 0.f);
            }
        }
    }

    f32x4 acc2[8][2];
#pragma unroll
    for (int n = 0; n < 8; n++) {
        acc2[n][0] = (f32x4){0.f, 0.f, 0.f, 0.f};
        acc2[n][1] = (f32x4){0.f, 0.f, 0.f, 0.f};
    }
#pragma unroll
    for (int t = 0; t < 8; t++) {
        s16x8 a0 = *(const s16x8*)&hbuf[w * 32 + m][t * 32 + q * 8];
        s16x8 a1 = *(const s16x8*)&hbuf[w * 32 + 16 + m][t * 32 + q * 8];
        const short* wp = U2s + (t * 8) * 512 + lane * 8;
#pragma unroll
        for (int n = 0; n < 8; n++) {
            s16x8 b = *(const s16x8*)(wp + n * 512);
            acc2[n][0] = MFMA(a0, b, acc2[n][0]);
            acc2[n][1] = MFMA(a1, b, acc2[n][1]);
        }
    }

#pragma unroll
    for (int mb = 0; mb < 2; mb++) {
#pragma unroll
        for (int r = 0; r < 4; r++) {
            int orow = r0 + mb * 16 + q * 4 + r;
            if (orow < NN) {
#pragma unroll
                for (int n = 0; n < 8; n++) {
                    out[(long)orow * D + n * 16 + m] = acc2[n][mb][r] + b2[n * 16 + m];
                }
            }
        }
    }
}

extern "C" void kernel_launch(void* const* d_in, const int* in_sizes, int n_in,
                              void* d_out, int out_size, void* d_ws, size_t ws_size,
                              hipStream_t stream) {
    const float* x     = (const float*)d_in[0];
    const int*   ei    = (const int*)d_in[1];
    const float* eattr = (const float*)d_in[2];
    const float* cong  = (const float*)d_in[3];
    const float* mW1   = (const float*)d_in[4];
    const float* mb1   = (const float*)d_in[5];
    const float* mW2   = (const float*)d_in[6];
    const float* mb2   = (const float*)d_in[7];
    const float* uW1   = (const float*)d_in[8];
    const float* ub1   = (const float*)d_in[9];
    const float* uW2   = (const float*)d_in[10];
    const float* ub2   = (const float*)d_in[11];

    char* ws = (char*)d_ws;
    float* agg    = (float*)ws;                     // 51,200,000 B
    short* xb     = (short*)(ws + 51200000);        // 25,600,000 B
    short* W1s    = (short*)(ws + 76800000);        //    163,840 B (K padded 289->320)
    short* W2s    = (short*)(ws + 76963840);        //     65,536 B
    short* U1s    = (short*)(ws + 77029376);        //    131,072 B
    short* U2s    = (short*)(ws + 77160448);        //     65,536 B
    int*   cnt    = (int*)(ws + 77225984);          //    400,000 B (cursor after scan)
    int*   perm   = (int*)(ws + 77625984);          //  6,400,000 B
    int2*  srcdst = (int2*)(ws + 84025984);         // 12,800,000 B
    int*   psum   = (int*)(ws + 96825984);          //        512 B (block partials)

    hipMemsetAsync(agg, 0, (size_t)NN * D * sizeof(float), stream);
    hipMemsetAsync(cnt, 0, (size_t)NN * sizeof(int), stream);

    k_cvt_x<<<(NN * D / 4 + 255) / 256, 256, 0, stream>>>(x, xb, NN * D);

    int tW1 = 10 * 16 * 512, tW2 = 8 * 8 * 512, tU1 = 8 * 16 * 512, tU2 = 8 * 8 * 512;
    k_swz<<<(tW1 + 255) / 256, 256, 0, stream>>>(mW1, W1s, 289, 256, tW1);
    k_swz<<<(tW2 + 255) / 256, 256, 0, stream>>>(mW2, W2s, 256, 128, tW2);
    k_swz<<<(tU1 + 255) / 256, 256, 0, stream>>>(uW1, U1s, 256, 256, tU1);
    k_swz<<<(tU2 + 255) / 256, 256, 0, stream>>>(uW2, U2s, 256, 128, tU2);

    // counting sort by dst (hierarchical scan: parallel across CUs)
    int nb = (NN + 1023) / 1024;   // 98
    k_hist<<<(E_TOTAL + 255) / 256, 256, 0, stream>>>(ei, cnt);
    k_scan1<<<nb, 1024, 0, stream>>>(cnt, psum, NN);
    k_scan2<<<1, 128, 0, stream>>>(psum, nb);
    k_scan3<<<nb, 1024, 0, stream>>>(psum, cnt, NN);
    k_perm<<<(E_TOTAL + 255) / 256, 256, 0, stream>>>(ei, cnt, perm, srcdst);

    // 128 sorted edges per 256-thread block (4 waves x 32)
    k_edge<<<E_TOTAL / 128, 256, 0, stream>>>(xb, perm, srcdst, eattr, cong,
                                              W1s, mb1, W2s, mb2, agg);
    k_node<<<(NN + 63) / 64, 128, 0, stream>>>(xb, agg, U1s, ub1, U2s, ub2, (float*)d_out);
}